// Round 1
// baseline (786.553 us; speedup 1.0000x reference)
//
#include <hip/hip_runtime.h>
#include <math.h>

// CMCD sampler: 8 sequential Langevin steps.
// Design: bf16 MFMA (16x16x32) one-wave-per-tile direct-from-global for all
// matmuls; fp32 for trajectory-critical math. Median via 65536-bin linear
// histogram on d2 with interpolation (h_t sensitivity is negligible).
// 50 kernel nodes total: prep1, prep2, 8 x (gram, L0+median, L1, L2, L3, update).

typedef __attribute__((ext_vector_type(8))) short short8;
typedef __attribute__((ext_vector_type(4))) float floatx4;
typedef unsigned int u32;
typedef unsigned short u16;

// ---- workspace byte offsets (total ~4.3 MB) ----
#define WS_TE      0u         // f32[8*512]  te + in_b per step
#define WS_G1      16384u     // f32[8*512]  t-MLP hidden
#define WS_BETAS   32768u     // f32[16]
#define WS_HT      32832u     // f32[4]
#define WS_NORMS   33024u     // f32[512]
#define WS_D2      36864u     // f32[512*512]
#define WS_HIST    1085440u   // u32[65536]
#define WS_XBF     1347584u   // u16[512*64]   x in bf16
#define WS_XBFT    1413120u   // u16[64*512]   x^T in bf16 (parity 0)
#define WS_INWT    1478656u   // u16[512*64]   in_W^T bf16
#define WS_OUTWT   1544192u   // u16[64*512]   out_W^T bf16
#define WS_HWT     1609728u   // u16[3*512*512] h_W^T bf16
#define WS_HB0     3182592u   // u16[512*512]  h ping
#define WS_HB1     3706880u   // u16[512*512]  h pong
#define WS_XBFT1   4231168u   // u16[64*512]   x^T bf16 (parity 1)

__device__ __forceinline__ u16 f2bf(float f) {
  u32 u = __float_as_uint(f);
  u32 r = u + 0x7FFFu + ((u >> 16) & 1u);
  return (u16)(r >> 16);
}

// tanh-approx gelu (jax.nn.gelu default approximate=True)
__device__ __forceinline__ float gelu_f(float x) {
  float y = 0.7978845608028654f * (x + 0.044715f * x * x * x);
  float ay = fabsf(y);
  float e = __expf(-2.0f * ay);
  float t = (1.0f - e) / (1.0f + e);
  t = (y < 0.0f) ? -t : t;
  return 0.5f * x * (1.0f + t);
}

// ---------------- prep1: weights->bf16T, x copies, norms, betas, g1, hist=0 ----
__global__ __launch_bounds__(256) void prep1(
    const float* __restrict__ particles, const float* __restrict__ grid_t,
    const float* __restrict__ phase, const float* __restrict__ in_W,
    const float* __restrict__ h_W, const float* __restrict__ out_W,
    const float* __restrict__ t_W1, const float* __restrict__ t_b1,
    float* __restrict__ d_out, char* ws)
{
  int b = blockIdx.x, t = threadIdx.x;
  if (b < 16) {
    // g1[i][c] = gelu(temb @ t_W1 + t_b1), temb = [sin(emb), cos(emb)]
    __shared__ float temb[1024];
    int i = b >> 1, half = b & 1;
    float fi = (float)i;
    for (int jj = 0; jj < 2; jj++) {
      int kk = jj * 256 + t;
      float cf = 0.1f + (float)kk * (99.9f / 511.0f);   // linspace(0.1,100,512)
      float e = cf * fi + phase[kk];
      temb[kk] = sinf(e);
      temb[512 + kk] = cosf(e);
    }
    __syncthreads();
    int c = half * 256 + t;
    float acc = t_b1[c];
    for (int k = 0; k < 1024; k++) acc = fmaf(temb[k], t_W1[k * 512 + c], acc);
    ((float*)(ws + WS_G1))[i * 512 + c] = gelu_f(acc);
  } else if (b < 432) {
    u16* hWT = (u16*)(ws + WS_HWT);
    u16* inWT = (u16*)(ws + WS_INWT);
    u16* outWT = (u16*)(ws + WS_OUTWT);
    for (u32 e = (u32)(b - 16) * 256u + (u32)t; e < 851968u; e += 106496u) {
      if (e < 786432u) {
        u32 l = e >> 18, rem = e & 262143u, c = rem >> 9, k = rem & 511u;
        hWT[e] = f2bf(h_W[l * 262144u + k * 512u + c]);
      } else if (e < 819200u) {
        u32 e2 = e - 786432u, c = e2 >> 6, k = e2 & 63u;
        inWT[e2] = f2bf(in_W[k * 512u + c]);
      } else {
        u32 e3 = e - 819200u, c = e3 >> 9, k = e3 & 511u;
        outWT[e3] = f2bf(out_W[k * 64u + c]);
      }
    }
  } else if (b == 432) {
    float* norms = (float*)(ws + WS_NORMS);
    for (int rr = t; rr < 512; rr += 256) {
      float s = 0.f;
      for (int d = 0; d < 64; d++) { float v = particles[rr * 64 + d]; s = fmaf(v, v, s); }
      norms[rr] = s;
    }
    if (t == 0) {
      float* betas = (float*)(ws + WS_BETAS);
      float sig[8]; float tot = 0.f;
      for (int j = 0; j < 8; j++) { sig[j] = 1.0f / (1.0f + __expf(-grid_t[j])); tot += sig[j]; }
      float cum = 0.f;
      betas[0] = 0.f;
      for (int j = 0; j < 8; j++) { cum += sig[j]; betas[j + 1] = cum / tot; }
    }
  } else if (b < 561) {
    u16* xbf = (u16*)(ws + WS_XBF);
    u16* xbfT = (u16*)(ws + WS_XBFT);
    u32 e = (u32)(b - 433) * 256u + (u32)t;   // < 32768
    float v = particles[e];
    d_out[e] = v;                              // traj row 0 = particles
    u16 bf = f2bf(v);
    xbf[e] = bf;
    xbfT[(e & 63u) * 512u + (e >> 6)] = bf;
  } else {
    u32* hist = (u32*)(ws + WS_HIST);
    u32 e = (u32)(b - 561) * 256u + (u32)t;   // < 65536
    hist[e] = 0u;
  }
}

// ---------------- prep2: te_tot[i][c] = g1[i] @ t_W2 + t_b2 + in_b ------------
__global__ __launch_bounds__(256) void prep2(
    const float* __restrict__ t_W2, const float* __restrict__ t_b2,
    const float* __restrict__ in_b, char* ws)
{
  __shared__ float g1row[512];
  int b = blockIdx.x, t = threadIdx.x;
  int i = b >> 1, half = b & 1;
  const float* g1 = (const float*)(ws + WS_G1);
  g1row[t] = g1[i * 512 + t];
  g1row[256 + t] = g1[i * 512 + 256 + t];
  __syncthreads();
  int c = half * 256 + t;
  float acc = t_b2[c] + in_b[c];
  for (int k = 0; k < 512; k++) acc = fmaf(g1row[k], t_W2[k * 512 + c], acc);
  ((float*)(ws + WS_TE))[i * 512 + c] = acc;
}

// ---------------- gram: d2 = n_i + n_j - 2*X X^T (bf16 MFMA) + histogram ------
__global__ __launch_bounds__(256) void gram_k(char* ws)
{
  const u16* xbf = (const u16*)(ws + WS_XBF);
  const float* norms = (const float*)(ws + WS_NORMS);
  float* d2 = (float*)(ws + WS_D2);
  u32* hist = (u32*)(ws + WS_HIST);
  int tid = threadIdx.x;
  int wv = tid >> 6, lane = tid & 63;
  int m = lane & 15, q = lane >> 4;
  int gw = blockIdx.x * 4 + wv;
  int r0 = (gw >> 5) * 16, c0 = (gw & 31) * 16;
  floatx4 acc = {0.f, 0.f, 0.f, 0.f};
#pragma unroll
  for (int kk = 0; kk < 2; kk++) {
    short8 a = *(const short8*)(xbf + (r0 + m) * 64 + kk * 32 + q * 8);
    short8 bfr = *(const short8*)(xbf + (c0 + m) * 64 + kk * 32 + q * 8);
    acc = __builtin_amdgcn_mfma_f32_16x16x32_bf16(a, bfr, acc, 0, 0, 0);
  }
  int col = c0 + m;
  float nc = norms[col];
#pragma unroll
  for (int rg = 0; rg < 4; rg++) {
    int row = r0 + q * 4 + rg;
    float v = norms[row] + nc - 2.0f * acc[rg];
    d2[row * 512 + col] = v;
    int bin = (int)(v * 64.0f);
    bin = bin < 0 ? 0 : (bin > 65535 ? 65535 : bin);
    atomicAdd(&hist[bin], 1u);
  }
}

// ---------------- dense: out = gelu(A @ BT^T + bias), bf16; optional median ---
__global__ __launch_bounds__(256) void dense_k(
    const u16* __restrict__ A, const u16* __restrict__ BT,
    const float* __restrict__ bias, u16* __restrict__ out,
    int K, const u32* __restrict__ hist, float* __restrict__ ht_out)
{
  if (ht_out && blockIdx.x == 256) {
    // sidecar: exact-rank (interpolated within 1/64-wide bin) median of d2
    __shared__ u32 scan_s[256];
    __shared__ float dmed[2];
    int t = threadIdx.x;
    const u32* h = hist + t * 256;
    u32 s = 0;
    for (int j = 0; j < 256; j++) s += h[j];
    scan_s[t] = s;
    __syncthreads();
    for (int off = 1; off < 256; off <<= 1) {
      u32 add = (t >= off) ? scan_s[t - off] : 0u;
      __syncthreads();
      scan_s[t] += add;
      __syncthreads();
    }
    u32 hi = scan_s[t], lo = hi - s;
    for (int tr = 0; tr < 2; tr++) {
      u32 R = 131071u + (u32)tr;   // two middle ranks of 262144
      if (R >= lo && R < hi) {
        u32 cum = lo;
        for (int j = 0; j < 256; j++) {
          u32 c = h[j];
          if (R < cum + c) {
            float d2v = ((float)(t * 256 + j) + ((float)(R - cum) + 0.5f) / (float)c) * (1.0f / 64.0f);
            dmed[tr] = sqrtf(fmaxf(d2v, 1e-12f));
            break;
          }
          cum += c;
        }
      }
    }
    __syncthreads();
    if (t == 0) {
      float md = 0.5f * (dmed[0] + dmed[1]);
      ht_out[0] = md * md / 6.2383246250395075f;  // log(512)
    }
    return;
  }
  int tid = threadIdx.x;
  int wv = tid >> 6, lane = tid & 63;
  int m = lane & 15, q = lane >> 4;
  int gw = blockIdx.x * 4 + wv;
  int r0 = (gw >> 5) * 16, c0 = (gw & 31) * 16;
  const u16* Ap = A + (r0 + m) * K + q * 8;
  const u16* Btp = BT + (c0 + m) * K + q * 8;
  floatx4 acc = {0.f, 0.f, 0.f, 0.f};
  int nk = K >> 5;
#pragma unroll 4
  for (int kk = 0; kk < nk; kk++) {
    short8 a = *(const short8*)(Ap + kk * 32);
    short8 bfr = *(const short8*)(Btp + kk * 32);
    acc = __builtin_amdgcn_mfma_f32_16x16x32_bf16(a, bfr, acc, 0, 0, 0);
  }
  int col = c0 + m;
  float bv = bias[col];
#pragma unroll
  for (int rg = 0; rg < 4; rg++) {
    int row = r0 + q * 4 + rg;
    out[row * 512 + col] = f2bf(gelu_f(acc[rg] + bv));
  }
}

// ---------------- update: score + grad_log_pi + repel + integrate -------------
__global__ __launch_bounds__(256) void update_k(
    const float* __restrict__ x_old, float* __restrict__ x_new,
    const float* __restrict__ noise_i, const float* __restrict__ eps,
    const float* __restrict__ mu, const float* __restrict__ out_b,
    char* ws, int step)
{
  const u16* h3 = (const u16*)(ws + WS_HB1);
  const u16* outWT = (const u16*)(ws + WS_OUTWT);
  const u16* xbfT_in = (const u16*)(ws + ((step & 1) ? WS_XBFT1 : WS_XBFT));
  u16* xbfT_out = (u16*)(ws + ((step & 1) ? WS_XBFT : WS_XBFT1));
  const float* d2 = (const float*)(ws + WS_D2);
  float inv_ht = 1.0f / ((const float*)(ws + WS_HT))[0];
  __shared__ float sc_s[16][64];
  __shared__ float s1_s[16][64];
  __shared__ float s0_s[16];
  __shared__ float comp_s[16][8];
  __shared__ float w8_s[16][8];
  __shared__ float wm_s[16][64];
  int tid = threadIdx.x;
  int wv = tid >> 6, lane = tid & 63;
  int m = lane & 15, q = lane >> 4;
  int r0 = blockIdx.x * 16;
  int c0 = wv * 16;   // d-dims
  floatx4 accS = {0.f, 0.f, 0.f, 0.f}, accR = {0.f, 0.f, 0.f, 0.f};
  float s0 = 0.f;
#pragma unroll 2
  for (int kk = 0; kk < 16; kk++) {
    short8 a = *(const short8*)(h3 + (r0 + m) * 512 + kk * 32 + q * 8);
    short8 bw = *(const short8*)(outWT + (c0 + m) * 512 + kk * 32 + q * 8);
    accS = __builtin_amdgcn_mfma_f32_16x16x32_bf16(a, bw, accS, 0, 0, 0);
    const float* dr = d2 + (r0 + m) * 512 + kk * 32 + q * 8;
    short8 wf;
#pragma unroll
    for (int j = 0; j < 8; j++) {
      float w = __expf(-dr[j] * inv_ht);
      s0 += w;
      wf[j] = (short)f2bf(w);
    }
    short8 bx = *(const short8*)(xbfT_in + (c0 + m) * 512 + kk * 32 + q * 8);
    accR = __builtin_amdgcn_mfma_f32_16x16x32_bf16(wf, bx, accR, 0, 0, 0);
  }
  s0 += __shfl_xor(s0, 16);
  s0 += __shfl_xor(s0, 32);
  int col = c0 + m;
  float ob = out_b[col];
#pragma unroll
  for (int rg = 0; rg < 4; rg++) {
    sc_s[q * 4 + rg][col] = accS[rg] + ob;
    s1_s[q * 4 + rg][col] = accR[rg];
  }
  if (wv == 0 && q == 0) s0_s[m] = s0;
  __syncthreads();
  if (tid < 128) {   // comp[r][mm] = -0.5*sum_d (x-mu)^2  (const cancels in softmax)
    int r = tid >> 3, mm = tid & 7;
    const float* xr = x_old + (r0 + r) * 64;
    const float* mr = mu + mm * 64;
    float s = 0.f;
    for (int d = 0; d < 64; d++) { float df = xr[d] - mr[d]; s = fmaf(df, df, s); }
    comp_s[r][mm] = -0.5f * s;
  }
  __syncthreads();
  if (tid < 16) {
    float mx = comp_s[tid][0];
    for (int j = 1; j < 8; j++) mx = fmaxf(mx, comp_s[tid][j]);
    float sm = 0.f; float e[8];
    for (int j = 0; j < 8; j++) { e[j] = __expf(comp_s[tid][j] - mx); sm += e[j]; }
    float inv = 1.0f / sm;
    for (int j = 0; j < 8; j++) w8_s[tid][j] = e[j] * inv;
  }
  __syncthreads();
  {
    int r = tid >> 4, db = (tid & 15) * 4;
    for (int j = 0; j < 4; j++) {
      float a = 0.f;
      for (int mm = 0; mm < 8; mm++) a = fmaf(w8_s[r][mm], mu[mm * 64 + db + j], a);
      wm_s[r][db + j] = a;
    }
  }
  __syncthreads();
  float tb = ((const float*)(ws + WS_BETAS))[step];
  float dt = eps[0];
  float sq = sqrtf(2.0f * dt);
  float* norms = (float*)(ws + WS_NORMS);
  u16* xbf = (u16*)(ws + WS_XBF);
  int r = tid >> 4, db = (tid & 15) * 4;
  int grow = r0 + r;
  float s0r = s0_s[r];
  float cR = -0.1f * inv_ht;
  float nn = 0.f;
#pragma unroll
  for (int j = 0; j < 4; j++) {
    float xv = x_old[grow * 64 + db + j];
    float g = -xv + tb * wm_s[r][db + j];                 // grad log pi
    float rep = cR * (xv * s0r - s1_s[r][db + j]);        // repel(x_old)
    float nv = xv + dt * (g - sc_s[r][db + j]) - dt * rep + sq * noise_i[grow * 64 + db + j];
    x_new[grow * 64 + db + j] = nv;
    u16 bf = f2bf(nv);
    xbf[grow * 64 + db + j] = bf;
    xbfT_out[(db + j) * 512 + grow] = bf;
    nn = fmaf(nv, nv, nn);
  }
#pragma unroll
  for (int off = 1; off < 16; off <<= 1) nn += __shfl_xor(nn, off);
  if ((tid & 15) == 0) norms[grow] = nn;
  // zero histogram for next step (consumed earlier this step; next writer is gram i+1)
  u32* hist = (u32*)(ws + WS_HIST);
  for (int e = tid; e < 2048; e += 256) hist[blockIdx.x * 2048 + e] = 0u;
}

extern "C" void kernel_launch(void* const* d_in, const int* in_sizes, int n_in,
                              void* d_out, int out_size, void* d_ws, size_t ws_size,
                              hipStream_t stream) {
  (void)in_sizes; (void)n_in; (void)out_size; (void)ws_size;
  const float* particles    = (const float*)d_in[0];
  const float* noises       = (const float*)d_in[1];
  const float* grid_t       = (const float*)d_in[2];
  const float* eps          = (const float*)d_in[3];
  const float* target_means = (const float*)d_in[4];
  const float* phase        = (const float*)d_in[5];
  const float* in_W         = (const float*)d_in[6];
  const float* in_b         = (const float*)d_in[7];
  const float* t_W1         = (const float*)d_in[8];
  const float* t_b1         = (const float*)d_in[9];
  const float* t_W2         = (const float*)d_in[10];
  const float* t_b2         = (const float*)d_in[11];
  const float* h_W          = (const float*)d_in[12];
  const float* h_b          = (const float*)d_in[13];
  const float* out_W        = (const float*)d_in[14];
  const float* out_b        = (const float*)d_in[15];
  float* out = (float*)d_out;
  char* ws = (char*)d_ws;

  prep1<<<817, 256, 0, stream>>>(particles, grid_t, phase, in_W, h_W, out_W, t_W1, t_b1, out, ws);
  prep2<<<16, 256, 0, stream>>>(t_W2, t_b2, in_b, ws);

  u16* hb0 = (u16*)(ws + WS_HB0);
  u16* hb1 = (u16*)(ws + WS_HB1);
  const u16* inWT = (const u16*)(ws + WS_INWT);
  const u16* hWT = (const u16*)(ws + WS_HWT);
  const u16* xbf = (const u16*)(ws + WS_XBF);
  const float* te = (const float*)(ws + WS_TE);
  const u32* hist = (const u32*)(ws + WS_HIST);
  float* ht = (float*)(ws + WS_HT);

  for (int i = 0; i < 8; i++) {
    gram_k<<<256, 256, 0, stream>>>(ws);
    dense_k<<<257, 256, 0, stream>>>(xbf, inWT, te + i * 512, hb0, 64, hist, ht);
    dense_k<<<256, 256, 0, stream>>>(hb0, hWT,          h_b,        hb1, 512, nullptr, nullptr);
    dense_k<<<256, 256, 0, stream>>>(hb1, hWT + 262144, h_b + 512,  hb0, 512, nullptr, nullptr);
    dense_k<<<256, 256, 0, stream>>>(hb0, hWT + 524288, h_b + 1024, hb1, 512, nullptr, nullptr);
    update_k<<<32, 256, 0, stream>>>(out + i * 32768, out + (i + 1) * 32768,
                                     noises + i * 32768, eps, target_means, out_b, ws, i);
  }
}

// Round 2
// 667.517 us; speedup vs baseline: 1.1783x; 1.1783x over previous
//
#include <hip/hip_runtime.h>
#include <math.h>

// CMCD sampler: 8 sequential Langevin steps.
// R1: coalesced transposes + K-split t-MLP/te (prep latency), gram+L0 fusion,
// K-split (8-wave) dense & update kernels for shorter dependency chains.
// Nodes: prep1, prep2, 8 x (gram+L0, L1+median, L2, L3, update) = 42.

typedef __attribute__((ext_vector_type(8))) short short8;
typedef __attribute__((ext_vector_type(4))) float floatx4;
typedef unsigned int u32;
typedef unsigned short u16;

// ---- workspace byte offsets (total ~4.5 MB) ----
#define WS_BETAS   32768u     // f32[16]
#define WS_HT      32832u     // f32[4]
#define WS_NORMS   33024u     // f32[512]
#define WS_D2      36864u     // f32[512*512]
#define WS_HIST    1085440u   // u32[65536]
#define WS_XBF     1347584u   // u16[512*64]   x in bf16
#define WS_XBFT    1413120u   // u16[64*512]   x^T bf16 (parity 0)
#define WS_INWT    1478656u   // u16[512*64]   in_W^T bf16
#define WS_OUTWT   1544192u   // u16[64*512]   out_W^T bf16
#define WS_HWT     1609728u   // u16[3*512*512] h_W^T bf16
#define WS_HB0     3182592u   // u16[512*512]  h ping
#define WS_HB1     3706880u   // u16[512*512]  h pong
#define WS_XBFT1   4231168u   // u16[64*512]   x^T bf16 (parity 1)
#define WS_G1P     4296704u   // f32[8 slices][8 i][512]  t-MLP pre-act partials
#define WS_TEP     4427776u   // f32[4 kq][8 i][512]      te partial slabs

__device__ __forceinline__ u16 f2bf(float f) {
  u32 u = __float_as_uint(f);
  u32 r = u + 0x7FFFu + ((u >> 16) & 1u);
  return (u16)(r >> 16);
}

// tanh-approx gelu (jax.nn.gelu default approximate=True)
__device__ __forceinline__ float gelu_f(float x) {
  float y = 0.7978845608028654f * (x + 0.044715f * x * x * x);
  float ay = fabsf(y);
  float e = __expf(-2.0f * ay);
  float t = (1.0f - e) / (1.0f + e);
  t = (y < 0.0f) ? -t : t;
  return 0.5f * x * (1.0f + t);
}

// ---------------- prep1 ------------------------------------------------------
// blocks [0,128):     t-MLP pre-act partials (slice,i,half), K-chain = 128
// blocks [128,960):   h_W transpose (LDS tile, coalesced both ways)
// blocks [960,992):   in_W transpose
// blocks [992,1024):  out_W transpose
// block  1024:        betas + particle norms
// blocks [1025,1153): x copies (d_out row0, xbf, xbfT)
// blocks [1153,1409): hist zero
__global__ __launch_bounds__(256) void prep1(
    const float* __restrict__ particles, const float* __restrict__ grid_t,
    const float* __restrict__ phase, const float* __restrict__ in_W,
    const float* __restrict__ h_W, const float* __restrict__ out_W,
    const float* __restrict__ t_W1, const float* __restrict__ t_b1,
    float* __restrict__ d_out, char* ws)
{
  int b = blockIdx.x, t = threadIdx.x;
  if (b < 128) {
    __shared__ float temb_s[128];
    int slice = b >> 4, i = (b >> 1) & 7, half = b & 1;
    float fi = (float)i;
    if (t < 128) {
      int kglob = slice * 128 + t;
      int kc = (kglob < 512) ? kglob : (kglob - 512);
      float cf = 0.1f + (float)kc * (99.9f / 511.0f);
      float e = cf * fi + phase[kc];
      temb_s[t] = (kglob < 512) ? sinf(e) : cosf(e);
    }
    __syncthreads();
    int c = half * 256 + t;
    float acc = (slice == 0) ? t_b1[c] : 0.0f;
    const float* wp = t_W1 + (u32)(slice * 128) * 512u + c;
#pragma unroll 8
    for (int kk = 0; kk < 128; kk++) acc = fmaf(temb_s[kk], wp[kk * 512], acc);
    ((float*)(ws + WS_G1P))[(slice * 8 + i) * 512 + c] = acc;
  } else if (b < 1024) {
    __shared__ float tile[32][33];
    int tx = t & 31, ty0 = t >> 5;
    const float* src; u16* dst; int sstr, dstr;
    if (b < 960) {
      int b2 = b - 128, l = b2 >> 8, kt = (b2 >> 4) & 15, ct = b2 & 15;
      src = h_W + l * 262144 + (kt * 32) * 512 + ct * 32; sstr = 512;
      dst = (u16*)(ws + WS_HWT) + l * 262144 + (ct * 32) * 512 + kt * 32; dstr = 512;
    } else if (b < 992) {
      int b3 = b - 960, kt = b3 >> 4, ct = b3 & 15;
      src = in_W + (kt * 32) * 512 + ct * 32; sstr = 512;
      dst = (u16*)(ws + WS_INWT) + (ct * 32) * 64 + kt * 32; dstr = 64;
    } else {
      int b4 = b - 992, kt = b4 & 15, ct = b4 >> 4;
      src = out_W + (kt * 32) * 64 + ct * 32; sstr = 64;
      dst = (u16*)(ws + WS_OUTWT) + (ct * 32) * 512 + kt * 32; dstr = 512;
    }
#pragma unroll
    for (int r = 0; r < 4; r++) { int ty = ty0 + r * 8; tile[ty][tx] = src[ty * sstr + tx]; }
    __syncthreads();
#pragma unroll
    for (int r = 0; r < 4; r++) { int ty = ty0 + r * 8; dst[ty * dstr + tx] = f2bf(tile[tx][ty]); }
  } else if (b == 1024) {
    float* norms = (float*)(ws + WS_NORMS);
    for (int rr = t; rr < 512; rr += 256) {
      float s = 0.f;
      const float* xr = particles + rr * 64;
#pragma unroll 8
      for (int d = 0; d < 64; d++) { float v = xr[d]; s = fmaf(v, v, s); }
      norms[rr] = s;
    }
    if (t == 0) {
      float* betas = (float*)(ws + WS_BETAS);
      float sig[8]; float tot = 0.f;
      for (int j = 0; j < 8; j++) { sig[j] = 1.0f / (1.0f + __expf(-grid_t[j])); tot += sig[j]; }
      float cum = 0.f;
      betas[0] = 0.f;
      for (int j = 0; j < 8; j++) { cum += sig[j]; betas[j + 1] = cum / tot; }
    }
  } else if (b < 1153) {
    u16* xbf = (u16*)(ws + WS_XBF);
    u16* xbfT = (u16*)(ws + WS_XBFT);
    u32 e = (u32)(b - 1025) * 256u + (u32)t;   // < 32768
    float v = particles[e];
    d_out[e] = v;
    u16 bf = f2bf(v);
    xbf[e] = bf;
    xbfT[(e & 63u) * 512u + (e >> 6)] = bf;
  } else {
    u32* hist = (u32*)(ws + WS_HIST);
    hist[(u32)(b - 1153) * 256u + (u32)t] = 0u;
  }
}

// ---------------- prep2: te partial slabs ------------------------------------
// 32 blocks x 512 thr: block=(i,kq). g1 = gelu(sum of 8 pre-act partials) for
// this kq's 128 k's, then partial te[kq][i][c] = g1 @ t_W2 slice (+biases on kq0).
__global__ __launch_bounds__(512) void prep2(
    const float* __restrict__ t_W2, const float* __restrict__ t_b2,
    const float* __restrict__ in_b, char* ws)
{
  __shared__ float g1_s[128];
  int b = blockIdx.x, t = threadIdx.x;
  int i = b >> 2, kq = b & 3;
  const float* g1p = (const float*)(ws + WS_G1P);
  if (t < 128) {
    int kglob = kq * 128 + t;
    float s = 0.f;
#pragma unroll
    for (int sl = 0; sl < 8; sl++) s += g1p[(sl * 8 + i) * 512 + kglob];
    g1_s[t] = gelu_f(s);
  }
  __syncthreads();
  int c = t;
  float acc = (kq == 0) ? (t_b2[c] + in_b[c]) : 0.0f;
  const float* wp = t_W2 + (u32)(kq * 128) * 512u + c;
#pragma unroll 8
  for (int kk = 0; kk < 128; kk++) acc = fmaf(g1_s[kk], wp[kk * 512], acc);
  ((float*)(ws + WS_TEP))[(kq * 8 + i) * 512 + c] = acc;
}

// ---------------- gram + L0 fused (512 thr = 8 tile-waves/block) -------------
// blocks [0,128): gram d2 + hist.  blocks [128,256): L0 = gelu(x@in_W + te).
__global__ __launch_bounds__(512) void gram_l0(char* ws, const float* __restrict__ te)
{
  const u16* xbf = (const u16*)(ws + WS_XBF);
  int tid = threadIdx.x;
  int wv = tid >> 6, lane = tid & 63;
  int m = lane & 15, q = lane >> 4;
  if (blockIdx.x < 128) {
    const float* norms = (const float*)(ws + WS_NORMS);
    float* d2 = (float*)(ws + WS_D2);
    u32* hist = (u32*)(ws + WS_HIST);
    int gw = blockIdx.x * 8 + wv;
    int r0 = (gw >> 5) * 16, c0 = (gw & 31) * 16;
    floatx4 acc = {0.f, 0.f, 0.f, 0.f};
#pragma unroll
    for (int kk = 0; kk < 2; kk++) {
      short8 a = *(const short8*)(xbf + (r0 + m) * 64 + kk * 32 + q * 8);
      short8 bfr = *(const short8*)(xbf + (c0 + m) * 64 + kk * 32 + q * 8);
      acc = __builtin_amdgcn_mfma_f32_16x16x32_bf16(a, bfr, acc, 0, 0, 0);
    }
    int col = c0 + m;
    float nc = norms[col];
#pragma unroll
    for (int rg = 0; rg < 4; rg++) {
      int row = r0 + q * 4 + rg;
      float v = norms[row] + nc - 2.0f * acc[rg];
      d2[row * 512 + col] = v;
      int bin = (int)(v * 64.0f);
      bin = bin < 0 ? 0 : (bin > 65535 ? 65535 : bin);
      atomicAdd(&hist[bin], 1u);
    }
  } else {
    const u16* inWT = (const u16*)(ws + WS_INWT);
    u16* hb0 = (u16*)(ws + WS_HB0);
    int gw = (blockIdx.x - 128) * 8 + wv;
    int r0 = (gw >> 5) * 16, c0 = (gw & 31) * 16;
    floatx4 acc = {0.f, 0.f, 0.f, 0.f};
#pragma unroll
    for (int kk = 0; kk < 2; kk++) {
      short8 a = *(const short8*)(xbf + (r0 + m) * 64 + kk * 32 + q * 8);
      short8 bfr = *(const short8*)(inWT + (c0 + m) * 64 + kk * 32 + q * 8);
      acc = __builtin_amdgcn_mfma_f32_16x16x32_bf16(a, bfr, acc, 0, 0, 0);
    }
    int col = c0 + m;
    float bv = te[col] + te[4096 + col] + te[8192 + col] + te[12288 + col];
#pragma unroll
    for (int rg = 0; rg < 4; rg++)
      hb0[(r0 + q * 4 + rg) * 512 + col] = f2bf(gelu_f(acc[rg] + bv));
  }
}

// ---------------- dense (K=512, K-split over wave pairs) + median sidecar ----
__global__ __launch_bounds__(512) void dense_ks(
    const u16* __restrict__ A, const u16* __restrict__ BT,
    const float* __restrict__ bias, u16* __restrict__ out,
    const u32* __restrict__ hist, float* __restrict__ ht_out)
{
  if (ht_out && blockIdx.x == 256) {
    __shared__ u32 scan_s[512];
    __shared__ float dmed[2];
    int t = threadIdx.x;
    const u32* h = hist + t * 128;
    u32 s = 0;
    for (int j = 0; j < 128; j++) s += h[j];
    scan_s[t] = s;
    __syncthreads();
    for (int off = 1; off < 512; off <<= 1) {
      u32 add = (t >= off) ? scan_s[t - off] : 0u;
      __syncthreads();
      scan_s[t] += add;
      __syncthreads();
    }
    u32 hi = scan_s[t], lo = hi - s;
    for (int tr = 0; tr < 2; tr++) {
      u32 R = 131071u + (u32)tr;
      if (R >= lo && R < hi) {
        u32 cum = lo;
        for (int j = 0; j < 128; j++) {
          u32 c = h[j];
          if (R < cum + c) {
            float d2v = ((float)(t * 128 + j) + ((float)(R - cum) + 0.5f) / (float)c) * (1.0f / 64.0f);
            dmed[tr] = sqrtf(fmaxf(d2v, 1e-12f));
            break;
          }
          cum += c;
        }
      }
    }
    __syncthreads();
    if (t == 0) {
      float md = 0.5f * (dmed[0] + dmed[1]);
      ht_out[0] = md * md / 6.2383246250395075f;  // log(512)
    }
    return;
  }
  int tid = threadIdx.x;
  int wv = tid >> 6, lane = tid & 63;
  int m = lane & 15, q = lane >> 4;
  int tile = wv & 3, kh = wv >> 2;
  int gw = blockIdx.x * 4 + tile;
  int r0 = (gw >> 5) * 16, c0 = (gw & 31) * 16;
  const u16* Ap = A + (r0 + m) * 512 + kh * 256 + q * 8;
  const u16* Bp = BT + (c0 + m) * 512 + kh * 256 + q * 8;
  floatx4 acc = {0.f, 0.f, 0.f, 0.f};
#pragma unroll
  for (int kk = 0; kk < 8; kk++) {
    short8 a = *(const short8*)(Ap + kk * 32);
    short8 bfr = *(const short8*)(Bp + kk * 32);
    acc = __builtin_amdgcn_mfma_f32_16x16x32_bf16(a, bfr, acc, 0, 0, 0);
  }
  __shared__ float comb[4][64][4];
  if (kh) {
#pragma unroll
    for (int rg = 0; rg < 4; rg++) comb[tile][lane][rg] = acc[rg];
  }
  __syncthreads();
  if (!kh) {
    int col = c0 + m;
    float bv = bias[col];
#pragma unroll
    for (int rg = 0; rg < 4; rg++)
      out[(r0 + q * 4 + rg) * 512 + col] = f2bf(gelu_f(acc[rg] + comb[tile][lane][rg] + bv));
  }
}

// ---------------- update: score + grad_log_pi + repel + integrate ------------
// 32 blocks x 512 thr: waves (ct 0..3, kh 0..1) K-split both MFMA chains.
__global__ __launch_bounds__(512) void update_k(
    const float* __restrict__ x_old, float* __restrict__ x_new,
    const float* __restrict__ noise_i, const float* __restrict__ eps,
    const float* __restrict__ mu, const float* __restrict__ out_b,
    char* ws, int step)
{
  const u16* h3 = (const u16*)(ws + WS_HB1);
  const u16* outWT = (const u16*)(ws + WS_OUTWT);
  const u16* xbfT_in = (const u16*)(ws + ((step & 1) ? WS_XBFT1 : WS_XBFT));
  u16* xbfT_out = (u16*)(ws + ((step & 1) ? WS_XBFT : WS_XBFT1));
  const float* d2 = (const float*)(ws + WS_D2);
  float inv_ht = 1.0f / ((const float*)(ws + WS_HT))[0];
  __shared__ float sc_s[16][64];
  __shared__ float s1_s[16][64];
  __shared__ float s0_s[16];
  __shared__ float s0h_s[16];
  __shared__ float combS[4][64][4];
  __shared__ float combR[4][64][4];
  __shared__ float comp_s[16][8];
  __shared__ float w8_s[16][8];
  __shared__ float wm_s[16][64];
  int tid = threadIdx.x;
  int wv = tid >> 6, lane = tid & 63;
  int m = lane & 15, q = lane >> 4;
  int ct = wv & 3, kh = wv >> 2;
  int r0 = blockIdx.x * 16;
  int c0 = ct * 16;
  floatx4 accS = {0.f, 0.f, 0.f, 0.f}, accR = {0.f, 0.f, 0.f, 0.f};
  float s0 = 0.f;
#pragma unroll
  for (int kk = kh * 8; kk < kh * 8 + 8; kk++) {
    short8 a = *(const short8*)(h3 + (r0 + m) * 512 + kk * 32 + q * 8);
    short8 bw = *(const short8*)(outWT + (c0 + m) * 512 + kk * 32 + q * 8);
    accS = __builtin_amdgcn_mfma_f32_16x16x32_bf16(a, bw, accS, 0, 0, 0);
    const float4* dr = (const float4*)(d2 + (r0 + m) * 512 + kk * 32 + q * 8);
    float4 dv0 = dr[0], dv1 = dr[1];
    float dvals[8] = {dv0.x, dv0.y, dv0.z, dv0.w, dv1.x, dv1.y, dv1.z, dv1.w};
    short8 wf;
#pragma unroll
    for (int j = 0; j < 8; j++) {
      float w = __expf(-dvals[j] * inv_ht);
      s0 += w;
      wf[j] = (short)f2bf(w);
    }
    short8 bx = *(const short8*)(xbfT_in + (c0 + m) * 512 + kk * 32 + q * 8);
    accR = __builtin_amdgcn_mfma_f32_16x16x32_bf16(wf, bx, accR, 0, 0, 0);
  }
  s0 += __shfl_xor(s0, 16);
  s0 += __shfl_xor(s0, 32);
  if (kh) {
#pragma unroll
    for (int rg = 0; rg < 4; rg++) { combS[ct][lane][rg] = accS[rg]; combR[ct][lane][rg] = accR[rg]; }
    if (wv == 4 && q == 0) s0h_s[m] = s0;
  }
  __syncthreads();
  if (!kh) {
    int col = c0 + m;
    float ob = out_b[col];
#pragma unroll
    for (int rg = 0; rg < 4; rg++) {
      sc_s[q * 4 + rg][col] = accS[rg] + combS[ct][lane][rg] + ob;
      s1_s[q * 4 + rg][col] = accR[rg] + combR[ct][lane][rg];
    }
    if (wv == 0 && q == 0) s0_s[m] = s0 + s0h_s[m];
  }
  __syncthreads();
  if (tid < 128) {   // comp[r][mm] = -0.5*sum_d (x-mu)^2 (const cancels in softmax)
    int r = tid >> 3, mm = tid & 7;
    const float* xr = x_old + (r0 + r) * 64;
    const float* mr = mu + mm * 64;
    float s = 0.f;
#pragma unroll 8
    for (int d = 0; d < 64; d++) { float df = xr[d] - mr[d]; s = fmaf(df, df, s); }
    comp_s[r][mm] = -0.5f * s;
  }
  __syncthreads();
  if (tid < 16) {
    float mx = comp_s[tid][0];
    for (int j = 1; j < 8; j++) mx = fmaxf(mx, comp_s[tid][j]);
    float sm = 0.f; float e[8];
    for (int j = 0; j < 8; j++) { e[j] = __expf(comp_s[tid][j] - mx); sm += e[j]; }
    float inv = 1.0f / sm;
    for (int j = 0; j < 8; j++) w8_s[tid][j] = e[j] * inv;
  }
  __syncthreads();
  if (tid < 256) {
    int r = tid >> 4, db = (tid & 15) * 4;
    for (int j = 0; j < 4; j++) {
      float a = 0.f;
      for (int mm = 0; mm < 8; mm++) a = fmaf(w8_s[r][mm], mu[mm * 64 + db + j], a);
      wm_s[r][db + j] = a;
    }
  }
  __syncthreads();
  if (tid < 256) {
    float tb = ((const float*)(ws + WS_BETAS))[step];
    float dt = eps[0];
    float sq = sqrtf(2.0f * dt);
    float* norms = (float*)(ws + WS_NORMS);
    u16* xbf = (u16*)(ws + WS_XBF);
    int r = tid >> 4, db = (tid & 15) * 4;
    int grow = r0 + r;
    float s0r = s0_s[r];
    float cR = -0.1f * inv_ht;
    float nn = 0.f;
#pragma unroll
    for (int j = 0; j < 4; j++) {
      float xv = x_old[grow * 64 + db + j];
      float g = -xv + tb * wm_s[r][db + j];                 // grad log pi
      float rep = cR * (xv * s0r - s1_s[r][db + j]);        // repel(x_old)
      float nv = xv + dt * (g - sc_s[r][db + j]) - dt * rep + sq * noise_i[grow * 64 + db + j];
      x_new[grow * 64 + db + j] = nv;
      u16 bf = f2bf(nv);
      xbf[grow * 64 + db + j] = bf;
      xbfT_out[(db + j) * 512 + grow] = bf;
      nn = fmaf(nv, nv, nn);
    }
#pragma unroll
    for (int off = 1; off < 16; off <<= 1) nn += __shfl_xor(nn, off);
    if ((tid & 15) == 0) norms[grow] = nn;
  }
  u32* hist = (u32*)(ws + WS_HIST);
  for (int e = tid; e < 2048; e += 512) hist[blockIdx.x * 2048 + e] = 0u;
}

extern "C" void kernel_launch(void* const* d_in, const int* in_sizes, int n_in,
                              void* d_out, int out_size, void* d_ws, size_t ws_size,
                              hipStream_t stream) {
  (void)in_sizes; (void)n_in; (void)out_size; (void)ws_size;
  const float* particles    = (const float*)d_in[0];
  const float* noises       = (const float*)d_in[1];
  const float* grid_t       = (const float*)d_in[2];
  const float* eps          = (const float*)d_in[3];
  const float* target_means = (const float*)d_in[4];
  const float* phase        = (const float*)d_in[5];
  const float* in_W         = (const float*)d_in[6];
  const float* in_b         = (const float*)d_in[7];
  const float* t_W1         = (const float*)d_in[8];
  const float* t_b1         = (const float*)d_in[9];
  const float* t_W2         = (const float*)d_in[10];
  const float* t_b2         = (const float*)d_in[11];
  const float* h_W          = (const float*)d_in[12];
  const float* h_b          = (const float*)d_in[13];
  const float* out_W        = (const float*)d_in[14];
  const float* out_b        = (const float*)d_in[15];
  float* out = (float*)d_out;
  char* ws = (char*)d_ws;

  prep1<<<1409, 256, 0, stream>>>(particles, grid_t, phase, in_W, h_W, out_W, t_W1, t_b1, out, ws);
  prep2<<<32, 512, 0, stream>>>(t_W2, t_b2, in_b, ws);

  u16* hb0 = (u16*)(ws + WS_HB0);
  u16* hb1 = (u16*)(ws + WS_HB1);
  const u16* hWT = (const u16*)(ws + WS_HWT);
  const float* tep = (const float*)(ws + WS_TEP);
  const u32* hist = (const u32*)(ws + WS_HIST);
  float* ht = (float*)(ws + WS_HT);

  for (int i = 0; i < 8; i++) {
    gram_l0<<<256, 512, 0, stream>>>(ws, tep + i * 512);
    dense_ks<<<257, 512, 0, stream>>>(hb0, hWT,          h_b,        hb1, hist, ht);
    dense_ks<<<256, 512, 0, stream>>>(hb1, hWT + 262144, h_b + 512,  hb0, nullptr, nullptr);
    dense_ks<<<256, 512, 0, stream>>>(hb0, hWT + 524288, h_b + 1024, hb1, nullptr, nullptr);
    update_k<<<32, 512, 0, stream>>>(out + i * 32768, out + (i + 1) * 32768,
                                     noises + i * 32768, eps, target_means, out_b, ws, i);
  }
}